// Round 4
// baseline (1920.877 us; speedup 1.0000x reference)
//
#include <hip/hip_runtime.h>
#include <hip/hip_bf16.h>
#include <stdint.h>

// ---------------- problem constants ----------------
#define D_   1024
#define H_   16
#define HD_  64
#define F_   4096
#define NL_  4
#define B_   16
#define TT_  128
#define TS_  512
#define LP_  704
#define M_   (B_*LP_)

typedef __attribute__((ext_vector_type(8)))  __bf16 bf16x8;
typedef __attribute__((ext_vector_type(4)))  float  floatx4;

typedef __attribute__((address_space(3))) void lds_void_t;
typedef const __attribute__((address_space(1))) void g_void_t;

__device__ __forceinline__ void gl2lds16(const __bf16* g, const __bf16* l) {
  __builtin_amdgcn_global_load_lds((g_void_t*)g, (lds_void_t*)l, 16, 0, 0);
}

// ---------------- lens ----------------
__global__ void lens_kernel(const int* __restrict__ tmask, const int* __restrict__ smask,
                            int* __restrict__ lens) {
  __shared__ int red[256];
  int b = blockIdx.x, t = threadIdx.x;
  int tc = 0, sc = 0;
  if (t < TT_) tc = (tmask[b*TT_ + t] == 0) ? 1 : 0;
  for (int i = t; i < TS_; i += 256) sc += (smask[b*TS_ + i] == 0) ? 1 : 0;
  red[t] = tc + (sc << 16);
  __syncthreads();
  for (int s = 128; s > 0; s >>= 1) {
    if (t < s) red[t] += red[t + s];
    __syncthreads();
  }
  if (t == 0) {
    int tl = red[0] & 0xffff, sl = red[0] >> 16;
    if (tl < 0) tl = 0; if (tl > TT_) tl = TT_;
    if (sl < 0) sl = 0; if (sl > TS_) sl = TS_;
    int Lb = 2 + tl + sl;
    if (Lb > LP_) Lb = LP_;
    lens[2*b] = tl; lens[2*b+1] = Lb;
  }
}

// ---------------- plan ----------------
// plan[0]=Mtiles, plan[1]=Mused, plan[2+b]=off[b] (b=0..16)
__global__ void plan_kernel(const int* __restrict__ lens, int* __restrict__ plan) {
  if (threadIdx.x == 0 && blockIdx.x == 0) {
    int off = 0;
    for (int b = 0; b < B_; b++) {
      plan[2 + b] = off;
      int Lb = lens[2*b+1];
      int pad = ((Lb + 127) >> 7) << 7;
      if (pad > LP_) pad = LP_;
      off += pad;
    }
    plan[2 + B_] = off;
    plan[1] = off;
    plan[0] = (off + 127) >> 7;
  }
}

// ---------------- fp32 [R,C] -> bf16 [C,R] transpose (z-batched, out z-stride) ----------------
__global__ void transpose_kernel(const float* __restrict__ in, __bf16* __restrict__ out,
                                 int R, int C, long ozs) {
  __shared__ float tile[32][33];
  int x = threadIdx.x & 31, y0 = threadIdx.x >> 5;
  const float* inb = in + (size_t)blockIdx.z * R * C;
  __bf16* outb = out + (size_t)blockIdx.z * ozs;
  int r0 = blockIdx.y * 32, c0 = blockIdx.x * 32;
  #pragma unroll
  for (int i = 0; i < 4; i++) {
    int y = y0 + 8*i;
    tile[y][x] = inb[(size_t)(r0 + y)*C + c0 + x];
  }
  __syncthreads();
  #pragma unroll
  for (int i = 0; i < 4; i++) {
    int y = y0 + 8*i;
    outb[(size_t)(c0 + y)*R + r0 + x] = (__bf16)tile[x][y];
  }
}

// ---------------- build compacted x ----------------
__global__ void build_x_kernel(const float* __restrict__ text, const float* __restrict__ speech,
                               const float* __restrict__ cls, const float* __restrict__ sep,
                               const int* __restrict__ lens, const int* __restrict__ plan,
                               __bf16* __restrict__ xbf) {
  int b = blockIdx.y, l = blockIdx.x;
  int off = plan[2+b], padLb = plan[3+b] - off;
  if (l >= padLb) return;
  int tl = lens[2*b], Lb = lens[2*b+1];
  const float* src = nullptr;
  if (l == 0)              src = cls;
  else if (l <= tl)        src = text   + ((size_t)(l-1)*B_ + b)*D_;
  else if (l == tl + 1)    src = sep;
  else if (l < Lb)         src = speech + ((size_t)(l-2-tl)*B_ + b)*D_;
  __bf16* dst = xbf + (size_t)(off + l) * D_;
  #pragma unroll
  for (int j = 0; j < 4; j++) {
    int i = threadIdx.x + j*256;
    float v = src ? src[i] : 0.f;
    dst[i] = (__bf16)v;
  }
}

// ---------------- GEMM ----------------
// MODE 0: fp32 out (+bias); 2: bf16+relu; 5: fused QKV epilogue; 6: fp32 atomic splitK (no bias)
template<int MODE>
__global__ __launch_bounds__(256, 2)
void gemm_kernel(const __bf16* __restrict__ A, const __bf16* __restrict__ BT,
                 const float* __restrict__ bias, const float* __restrict__ bias2,
                 const float* __restrict__ bias3, void* __restrict__ Cv,
                 const int* __restrict__ plan, int Nn, int Kk, int Kloop, float scale) {
  if ((int)blockIdx.y >= plan[0]) return;
  __shared__ __bf16 As[128*32];
  __shared__ __bf16 Bs[128*32];
  int tid = threadIdx.x;
  int w = tid >> 6, l = tid & 63;
  int wm = w >> 1, wn = w & 1;
  long tile_m = (long)blockIdx.y * 128;
  long tile_n = (long)blockIdx.x * 128;
  long koff = (MODE == 6) ? (long)blockIdx.z * Kloop : 0;

  floatx4 acc[4][4] = {};

  const __bf16* ga = A  + (tile_m + w*32 + (l>>2)) * (long)Kk + (l&3)*8 + koff;
  const __bf16* gb = BT + (tile_n + w*32 + (l>>2)) * (long)Kk + (l&3)*8 + koff;
  const __bf16* lA = As + (w*32)*32;
  const __bf16* lB = Bs + (w*32)*32;

  int kcol = (l >> 4) * 8;
  const __bf16* afp = As + (wm*64 + (l&15))*32 + kcol;
  const __bf16* bfp = Bs + (wn*64 + (l&15))*32 + kcol;

  for (int k0 = 0; k0 < Kloop; k0 += 32) {
    gl2lds16(ga,               lA);
    gl2lds16(ga + 16*(long)Kk, lA + 16*32);
    gl2lds16(gb,               lB);
    gl2lds16(gb + 16*(long)Kk, lB + 16*32);
    ga += 32; gb += 32;
    __syncthreads();
    bf16x8 af[4], bf[4];
    #pragma unroll
    for (int mi = 0; mi < 4; mi++) af[mi] = *(const bf16x8*)(afp + mi*16*32);
    #pragma unroll
    for (int ni = 0; ni < 4; ni++) bf[ni] = *(const bf16x8*)(bfp + ni*16*32);
    #pragma unroll
    for (int mi = 0; mi < 4; mi++)
      #pragma unroll
      for (int ni = 0; ni < 4; ni++)
        acc[mi][ni] = __builtin_amdgcn_mfma_f32_16x16x32_bf16(af[mi], bf[ni], acc[mi][ni], 0, 0, 0);
    __syncthreads();
  }

  int rbase = wm*64 + (l>>4)*4;
  int cbase = wn*64 + (l&15);
  int seg = (int)(tile_n >> 10);      // uniform per block (tile_n mult of 128)
  #pragma unroll
  for (int mi = 0; mi < 4; mi++) {
    long row0 = tile_m + rbase + mi*16;
    long voff = 0;
    int bb = 0;
    if (MODE == 5) {                   // batch lookup for v-transpose segment
      #pragma unroll
      for (int t = 1; t < B_; t++) bb += (row0 >= plan[2+t]) ? 1 : 0;
      voff = plan[2+bb];
    }
    #pragma unroll
    for (int ni = 0; ni < 4; ni++) {
      long col = tile_n + cbase + ni*16;
      float bv;
      if (MODE == 5) {
        const float* bp = (seg == 0) ? bias : (seg == 1) ? bias2 : bias3;
        bv = bp[col & 1023];
      } else if (MODE == 6) {
        bv = 0.f;
      } else {
        bv = bias[col];
      }
      #pragma unroll
      for (int r = 0; r < 4; r++) {
        long row = row0 + r;
        float v = acc[mi][ni][r] + bv;
        if (MODE == 2) v = v > 0.f ? v : 0.f;
        if (MODE == 0)      ((float*)Cv)[row*Nn + col] = v;
        else if (MODE == 6) atomicAdd(&((float*)Cv)[row*Nn + col], v);
        else if (MODE == 5) {
          __bf16* base = (__bf16*)Cv;
          long c = col & 1023;
          if (seg == 0)       base[row*D_ + c] = (__bf16)(v * scale);
          else if (seg == 1)  base[(long)M_*D_ + row*D_ + c] = (__bf16)v;
          else {
            long ll = row - voff;
            if (ll < LP_)
              base[2L*M_*D_ + (((long)bb*H_ + (c>>6))*HD_ + (c&63))*LP_ + ll] = (__bf16)v;
          }
        }
        else                ((__bf16*)Cv)[row*Nn + col] = (__bf16)v;
      }
    }
  }
}

// ---------------- flash attention (compacted rows) ----------------
__global__ __launch_bounds__(256, 2)
void attn_kernel(const __bf16* __restrict__ qb, const __bf16* __restrict__ kb,
                 const __bf16* __restrict__ vt, __bf16* __restrict__ ob,
                 const int* __restrict__ lens, const int* __restrict__ plan) {
  int col = blockIdx.x;               // b*H + h
  int b = col >> 4;
  int off = plan[2+b];
  int padLb = plan[3+b] - off;
  if ((int)blockIdx.y * 128 >= padLb) return;
  __shared__ __bf16 Ks[64*64];
  __shared__ __bf16 Vs[64*64];
  __shared__ __bf16 Ps[4][32*72];
  int tid = threadIdx.x, w = tid >> 6, l = tid & 63;
  int Lb = lens[2*b+1];
  int q0w = blockIdx.y*128 + w*32;
  const size_t bh  = (size_t)off*D_ + (size_t)(col & 15)*HD_;
  const size_t vtb = (size_t)col * HD_ * LP_;
  int nkt = (Lb + 63) >> 6;

  bf16x8 qf[2][2];
  #pragma unroll
  for (int mi = 0; mi < 2; mi++) {
    int qr = q0w + mi*16 + (l&15);
    if (qr > padLb-1) qr = padLb-1;
    const __bf16* qp = qb + bh + (size_t)qr*D_ + (l>>4)*8;
    qf[mi][0] = *(const bf16x8*)(qp);
    qf[mi][1] = *(const bf16x8*)(qp + 32);
  }
  bf16x8 ones;
  #pragma unroll
  for (int j = 0; j < 8; j++) ones[j] = (__bf16)1.0f;

  floatx4 oacc[2][4] = {};
  floatx4 lacc[2] = {};

  for (int kt = 0; kt < nkt; kt++) {
    int kbase = kt*64;
    {
      int krow = w*16 + (l>>3);
      int cb = (l&7) ^ (krow & 7);
      const __bf16* gk = kb + bh + (size_t)(kbase + krow)*D_ + cb*8;
      const __bf16* lk = Ks + (w*16)*64;
      gl2lds16(gk,                lk);
      gl2lds16(gk + 8*(size_t)D_, lk + 8*64);
    }
    {
      int vrow = w*8 + (l>>3);
      int sb = (l&7) ^ (l>>3);
      const __bf16* gv = vt + vtb + (size_t)vrow*LP_ + kbase + sb*8;
      const __bf16* lv = Vs + (w*8)*64;
      gl2lds16(gv,                  lv);
      gl2lds16(gv + 32*(size_t)LP_, lv + 32*64);
    }
    __syncthreads();

    floatx4 s4[2][4] = {};
    #pragma unroll
    for (int ks = 0; ks < 2; ks++) {
      #pragma unroll
      for (int ni = 0; ni < 4; ni++) {
        int n = ni*16 + (l&15);
        int blk = (ks*4 + (l>>4)) ^ (n & 7);
        bf16x8 kf = *(const bf16x8*)(Ks + n*64 + blk*8);
        s4[0][ni] = __builtin_amdgcn_mfma_f32_16x16x32_bf16(qf[0][ks], kf, s4[0][ni], 0, 0, 0);
        s4[1][ni] = __builtin_amdgcn_mfma_f32_16x16x32_bf16(qf[1][ks], kf, s4[1][ni], 0, 0, 0);
      }
    }
    #pragma unroll
    for (int mi = 0; mi < 2; mi++) {
      #pragma unroll
      for (int ni = 0; ni < 4; ni++) {
        int key = kbase + ni*16 + (l&15);
        bool valid = key < Lb;
        #pragma unroll
        for (int r = 0; r < 4; r++) {
          float sv = valid ? fminf(s4[mi][ni][r], 30.f) : -1e9f;
          float p = __expf(sv);
          Ps[w][(mi*16 + (l>>4)*4 + r)*72 + ni*16 + (l&15)] = (__bf16)p;
        }
      }
    }
    #pragma unroll
    for (int ks = 0; ks < 2; ks++) {
      bf16x8 pf0 = *(const bf16x8*)(&Ps[w][(l&15)*72 + ks*32 + (l>>4)*8]);
      bf16x8 pf1 = *(const bf16x8*)(&Ps[w][(16 + (l&15))*72 + ks*32 + (l>>4)*8]);
      lacc[0] = __builtin_amdgcn_mfma_f32_16x16x32_bf16(pf0, ones, lacc[0], 0, 0, 0);
      lacc[1] = __builtin_amdgcn_mfma_f32_16x16x32_bf16(pf1, ones, lacc[1], 0, 0, 0);
      #pragma unroll
      for (int ni = 0; ni < 4; ni++) {
        int n = ni*16 + (l&15);
        int blk = (ks*4 + (l>>4)) ^ (n & 7);
        bf16x8 vf = *(const bf16x8*)(Vs + n*64 + blk*8);
        oacc[0][ni] = __builtin_amdgcn_mfma_f32_16x16x32_bf16(pf0, vf, oacc[0][ni], 0, 0, 0);
        oacc[1][ni] = __builtin_amdgcn_mfma_f32_16x16x32_bf16(pf1, vf, oacc[1][ni], 0, 0, 0);
      }
    }
    __syncthreads();
  }

  #pragma unroll
  for (int mi = 0; mi < 2; mi++) {
    #pragma unroll
    for (int ni = 0; ni < 4; ni++) {
      #pragma unroll
      for (int r = 0; r < 4; r++) {
        int qrow = q0w + mi*16 + (l>>4)*4 + r;
        if (qrow < padLb) {
          float ov = oacc[mi][ni][r] / lacc[mi][r];
          ob[bh + (size_t)qrow*D_ + ni*16 + (l&15)] = (__bf16)ov;
        }
      }
    }
  }
}

// ---------------- post-norm LN (+ optional bias prefill of next tmp) ----------------
__global__ void ln_kernel(__bf16* __restrict__ x, const float* __restrict__ t,
                          const float* __restrict__ sc, const float* __restrict__ bi,
                          const int* __restrict__ plan,
                          float* __restrict__ pre, const float* __restrict__ preb) {
  int row = blockIdx.x;
  if (row >= plan[1]) return;
  __shared__ float red[2][4];
  int tid = threadIdx.x;
  const float* tr = t + (size_t)row * D_;
  __bf16* xr = x + (size_t)row * D_;
  float v[4], s1 = 0.f, s2 = 0.f;
  #pragma unroll
  for (int j = 0; j < 4; j++) {
    int i = tid + j*256;
    float val = (float)xr[i] + tr[i];
    v[j] = val; s1 += val; s2 += val*val;
  }
  #pragma unroll
  for (int off = 1; off < 64; off <<= 1) {
    s1 += __shfl_xor(s1, off, 64);
    s2 += __shfl_xor(s2, off, 64);
  }
  int w = tid >> 6, l = tid & 63;
  if (l == 0) { red[0][w] = s1; red[1][w] = s2; }
  __syncthreads();
  s1 = red[0][0] + red[0][1] + red[0][2] + red[0][3];
  s2 = red[1][0] + red[1][1] + red[1][2] + red[1][3];
  float mean = s1 * (1.f/D_);
  float var  = s2 * (1.f/D_) - mean*mean;
  float rstd = rsqrtf(var + 1e-5f);
  #pragma unroll
  for (int j = 0; j < 4; j++) {
    int i = tid + j*256;
    xr[i] = (__bf16)((v[j] - mean)*rstd*sc[i] + bi[i]);
    if (pre) pre[(size_t)row*D_ + i] = preb[i];   // seed next split-K accumulator with bias
  }
}

// ---------------- final ----------------
__global__ void out_kernel(const __bf16* __restrict__ x, const float* __restrict__ wv,
                           const int* __restrict__ plan, float* __restrict__ out) {
  __shared__ float red[4];
  int b = blockIdx.x, tid = threadIdx.x;
  const __bf16* xr = x + (size_t)plan[2+b] * D_;
  float s = 0.f;
  #pragma unroll
  for (int j = 0; j < 4; j++) {
    int i = tid + j*256;
    s += (float)xr[i] * wv[i];
  }
  #pragma unroll
  for (int off = 1; off < 64; off <<= 1) s += __shfl_xor(s, off, 64);
  int w = tid >> 6, l = tid & 63;
  if (l == 0) red[w] = s;
  __syncthreads();
  if (tid == 0) out[b] = red[0] + red[1] + red[2] + red[3];
}

// ---------------- launch ----------------
extern "C" void kernel_launch(void* const* d_in, const int* in_sizes, int n_in,
                              void* d_out, int out_size, void* d_ws, size_t ws_size,
                              hipStream_t stream) {
  (void)in_sizes; (void)n_in; (void)out_size; (void)ws_size;
  const float* text   = (const float*)d_in[0];
  const float* speech = (const float*)d_in[1];
  const int*   tmask  = (const int*)d_in[2];
  const int*   smask  = (const int*)d_in[3];
  const float* cls    = (const float*)d_in[4];
  const float* sep    = (const float*)d_in[5];
  const float* Wq     = (const float*)d_in[6];
  const float* bq     = (const float*)d_in[7];
  const float* Wk     = (const float*)d_in[8];
  const float* bk     = (const float*)d_in[9];
  const float* Wv     = (const float*)d_in[10];
  const float* bv     = (const float*)d_in[11];
  const float* Wo     = (const float*)d_in[12];
  const float* bo     = (const float*)d_in[13];
  const float* ln1s   = (const float*)d_in[14];
  const float* ln1b   = (const float*)d_in[15];
  const float* fc1w   = (const float*)d_in[16];
  const float* fc1b   = (const float*)d_in[17];
  const float* fc2w   = (const float*)d_in[18];
  const float* fc2b   = (const float*)d_in[19];
  const float* ln2s   = (const float*)d_in[20];
  const float* ln2b   = (const float*)d_in[21];
  const float* outw   = (const float*)d_in[22];

  const size_t MD = (size_t)M_ * D_;
  char* ws = (char*)d_ws;
  int*    lens = (int*)ws;
  int*    plan = (int*)(ws + 128);
  __bf16* xbf  = (__bf16*)(ws + 256);
  __bf16* act  = (__bf16*)(ws + 256 + MD*2);
  float*  tmp  = (float*) (ws + 256 + MD*2 + 4*MD*2);
  __bf16* wt   = (__bf16*)(ws + 256 + MD*2 + 4*MD*2 + MD*4);

  __bf16* qb   = act;
  __bf16* kb   = act + MD;
  __bf16* vtG  = act + 2*MD;                             // [B,H,HD,LP]
  __bf16* obuf = act + 3*MD;
  __bf16* hb   = act;                                    // [M, F] in FFN phase

  const size_t DD = (size_t)D_*D_;
  const size_t DF = (size_t)D_*F_;
  __bf16* wqkvT = wt;                                    // [NL][3*1024][1024]
  __bf16* woT   = wt + 12*DD;
  __bf16* fc1T  = wt + 16*DD;
  __bf16* fc2T  = wt + 16*DD + 4*DF;

  lens_kernel<<<B_, 256, 0, stream>>>(tmask, smask, lens);
  plan_kernel<<<1, 64, 0, stream>>>(lens, plan);

  transpose_kernel<<<dim3(D_/32, D_/32, NL_), 256, 0, stream>>>(Wq, wqkvT,        D_, D_, 3*DD);
  transpose_kernel<<<dim3(D_/32, D_/32, NL_), 256, 0, stream>>>(Wk, wqkvT + DD,   D_, D_, 3*DD);
  transpose_kernel<<<dim3(D_/32, D_/32, NL_), 256, 0, stream>>>(Wv, wqkvT + 2*DD, D_, D_, 3*DD);
  transpose_kernel<<<dim3(D_/32, D_/32, NL_), 256, 0, stream>>>(Wo, woT,  D_, D_, DD);
  transpose_kernel<<<dim3(F_/32, D_/32, NL_), 256, 0, stream>>>(fc1w, fc1T, D_, F_, DF);
  transpose_kernel<<<dim3(D_/32, F_/32, NL_), 256, 0, stream>>>(fc2w, fc2T, F_, D_, DF);

  build_x_kernel<<<dim3(LP_, B_), 256, 0, stream>>>(text, speech, cls, sep, lens, plan, xbf);

  for (int lyr = 0; lyr < NL_; lyr++) {
    // fused QKV: N=3072 packed weights; epilogue routes q(*0.125)/k/v(transposed)
    gemm_kernel<5><<<dim3(24, M_/128), 256, 0, stream>>>(
        xbf, wqkvT + (size_t)lyr*3*DD, bq + lyr*D_, bk + lyr*D_, bv + lyr*D_,
        act, plan, 3072, D_, D_, 0.125f);
    attn_kernel<<<dim3(B_*H_, (LP_+127)/128), 256, 0, stream>>>(qb, kb, vtG, obuf, lens, plan);
    gemm_kernel<0><<<dim3(D_/128, M_/128), 256, 0, stream>>>(
        obuf, woT + (size_t)lyr*DD, bo + lyr*D_, nullptr, nullptr, tmp, plan, D_, D_, D_, 1.f);
    // ln1 also seeds tmp with fc2 bias for the split-K accumulate
    ln_kernel<<<M_, 256, 0, stream>>>(xbf, tmp, ln1s + lyr*D_, ln1b + lyr*D_, plan,
                                      tmp, fc2b + lyr*D_);
    gemm_kernel<2><<<dim3(F_/128, M_/128), 256, 0, stream>>>(
        xbf, fc1T + (size_t)lyr*DF, fc1b + lyr*F_, nullptr, nullptr, hb, plan, F_, D_, D_, 1.f);
    // fc2 split-K=4: atomic fp32 accumulate into bias-seeded tmp
    gemm_kernel<6><<<dim3(D_/128, M_/128, 4), 256, 0, stream>>>(
        hb, fc2T + (size_t)lyr*DF, nullptr, nullptr, nullptr, tmp, plan, D_, F_, 1024, 1.f);
    ln_kernel<<<M_, 256, 0, stream>>>(xbf, tmp, ln2s + lyr*D_, ln2b + lyr*D_, plan,
                                      nullptr, nullptr);
  }

  out_kernel<<<B_, 256, 0, stream>>>(xbf, outw, plan, (float*)d_out);
}

// Round 5
// 1747.563 us; speedup vs baseline: 1.0992x; 1.0992x over previous
//
#include <hip/hip_runtime.h>
#include <hip/hip_bf16.h>
#include <stdint.h>

// ---------------- problem constants ----------------
#define D_   1024
#define H_   16
#define HD_  64
#define F_   4096
#define NL_  4
#define B_   16
#define TT_  128
#define TS_  512
#define LP_  704
#define M_   (B_*LP_)

typedef __attribute__((ext_vector_type(8)))  __bf16 bf16x8;
typedef __attribute__((ext_vector_type(4)))  float  floatx4;

typedef __attribute__((address_space(3))) void lds_void_t;
typedef const __attribute__((address_space(1))) void g_void_t;

__device__ __forceinline__ void gl2lds16(const __bf16* g, const __bf16* l) {
  __builtin_amdgcn_global_load_lds((g_void_t*)g, (lds_void_t*)l, 16, 0, 0);
}

// ---------------- lens ----------------
__global__ void lens_kernel(const int* __restrict__ tmask, const int* __restrict__ smask,
                            int* __restrict__ lens) {
  __shared__ int red[256];
  int b = blockIdx.x, t = threadIdx.x;
  int tc = 0, sc = 0;
  if (t < TT_) tc = (tmask[b*TT_ + t] == 0) ? 1 : 0;
  for (int i = t; i < TS_; i += 256) sc += (smask[b*TS_ + i] == 0) ? 1 : 0;
  red[t] = tc + (sc << 16);
  __syncthreads();
  for (int s = 128; s > 0; s >>= 1) {
    if (t < s) red[t] += red[t + s];
    __syncthreads();
  }
  if (t == 0) {
    int tl = red[0] & 0xffff, sl = red[0] >> 16;
    if (tl < 0) tl = 0; if (tl > TT_) tl = TT_;
    if (sl < 0) sl = 0; if (sl > TS_) sl = TS_;
    int Lb = 2 + tl + sl;
    if (Lb > LP_) Lb = LP_;
    lens[2*b] = tl; lens[2*b+1] = Lb;
  }
}

// ---------------- plan ----------------
// plan[0]=Mtiles, plan[1]=Mused, plan[2+b]=off[b] (b=0..16)
__global__ void plan_kernel(const int* __restrict__ lens, int* __restrict__ plan) {
  if (threadIdx.x == 0 && blockIdx.x == 0) {
    int off = 0;
    for (int b = 0; b < B_; b++) {
      plan[2 + b] = off;
      int Lb = lens[2*b+1];
      int pad = ((Lb + 127) >> 7) << 7;
      if (pad > LP_) pad = LP_;
      off += pad;
    }
    plan[2 + B_] = off;
    plan[1] = off;
    plan[0] = (off + 127) >> 7;
  }
}

// ---------------- fp32 [R,C] -> bf16 [C,R] transpose (z-batched, out z-stride) ----------------
__global__ void transpose_kernel(const float* __restrict__ in, __bf16* __restrict__ out,
                                 int R, int C, long ozs) {
  __shared__ float tile[32][33];
  int x = threadIdx.x & 31, y0 = threadIdx.x >> 5;
  const float* inb = in + (size_t)blockIdx.z * R * C;
  __bf16* outb = out + (size_t)blockIdx.z * ozs;
  int r0 = blockIdx.y * 32, c0 = blockIdx.x * 32;
  #pragma unroll
  for (int i = 0; i < 4; i++) {
    int y = y0 + 8*i;
    tile[y][x] = inb[(size_t)(r0 + y)*C + c0 + x];
  }
  __syncthreads();
  #pragma unroll
  for (int i = 0; i < 4; i++) {
    int y = y0 + 8*i;
    outb[(size_t)(c0 + y)*R + r0 + x] = (__bf16)tile[x][y];
  }
}

// ---------------- build compacted x ----------------
__global__ void build_x_kernel(const float* __restrict__ text, const float* __restrict__ speech,
                               const float* __restrict__ cls, const float* __restrict__ sep,
                               const int* __restrict__ lens, const int* __restrict__ plan,
                               __bf16* __restrict__ xbf) {
  int b = blockIdx.y, l = blockIdx.x;
  int off = plan[2+b], padLb = plan[3+b] - off;
  if (l >= padLb) return;
  int tl = lens[2*b], Lb = lens[2*b+1];
  const float* src = nullptr;
  if (l == 0)              src = cls;
  else if (l <= tl)        src = text   + ((size_t)(l-1)*B_ + b)*D_;
  else if (l == tl + 1)    src = sep;
  else if (l < Lb)         src = speech + ((size_t)(l-2-tl)*B_ + b)*D_;
  __bf16* dst = xbf + (size_t)(off + l) * D_;
  #pragma unroll
  for (int j = 0; j < 4; j++) {
    int i = threadIdx.x + j*256;
    float v = src ? src[i] : 0.f;
    dst[i] = (__bf16)v;
  }
}

// ---------------- GEMM ----------------
// MODE 0: fp32 out (+bias); 2: bf16+relu; 5: fused QKV epilogue;
// MODE 6: split-K fp32, plain store to Cv + z*MzStride, bias only on z==0
template<int MODE>
__global__ __launch_bounds__(256, 2)
void gemm_kernel(const __bf16* __restrict__ A, const __bf16* __restrict__ BT,
                 const float* __restrict__ bias, const float* __restrict__ bias2,
                 const float* __restrict__ bias3, void* __restrict__ Cv,
                 const int* __restrict__ plan, int Nn, int Kk, int Kloop, float scale) {
  if ((int)blockIdx.y >= plan[0]) return;
  __shared__ __bf16 As[128*32];
  __shared__ __bf16 Bs[128*32];
  int tid = threadIdx.x;
  int w = tid >> 6, l = tid & 63;
  int wm = w >> 1, wn = w & 1;
  long tile_m = (long)blockIdx.y * 128;
  long tile_n = (long)blockIdx.x * 128;
  long koff = (MODE == 6) ? (long)blockIdx.z * Kloop : 0;

  floatx4 acc[4][4] = {};

  const __bf16* ga = A  + (tile_m + w*32 + (l>>2)) * (long)Kk + (l&3)*8 + koff;
  const __bf16* gb = BT + (tile_n + w*32 + (l>>2)) * (long)Kk + (l&3)*8 + koff;
  const __bf16* lA = As + (w*32)*32;
  const __bf16* lB = Bs + (w*32)*32;

  int kcol = (l >> 4) * 8;
  const __bf16* afp = As + (wm*64 + (l&15))*32 + kcol;
  const __bf16* bfp = Bs + (wn*64 + (l&15))*32 + kcol;

  for (int k0 = 0; k0 < Kloop; k0 += 32) {
    gl2lds16(ga,               lA);
    gl2lds16(ga + 16*(long)Kk, lA + 16*32);
    gl2lds16(gb,               lB);
    gl2lds16(gb + 16*(long)Kk, lB + 16*32);
    ga += 32; gb += 32;
    __syncthreads();
    bf16x8 af[4], bf[4];
    #pragma unroll
    for (int mi = 0; mi < 4; mi++) af[mi] = *(const bf16x8*)(afp + mi*16*32);
    #pragma unroll
    for (int ni = 0; ni < 4; ni++) bf[ni] = *(const bf16x8*)(bfp + ni*16*32);
    #pragma unroll
    for (int mi = 0; mi < 4; mi++)
      #pragma unroll
      for (int ni = 0; ni < 4; ni++)
        acc[mi][ni] = __builtin_amdgcn_mfma_f32_16x16x32_bf16(af[mi], bf[ni], acc[mi][ni], 0, 0, 0);
    __syncthreads();
  }

  int rbase = wm*64 + (l>>4)*4;
  int cbase = wn*64 + (l&15);
  int seg = (int)(tile_n >> 10);      // uniform per block (tile_n mult of 128)
  float* outf = (float*)Cv;
  if (MODE == 6) outf += (long)blockIdx.z * ((long)M_ * D_);
  #pragma unroll
  for (int mi = 0; mi < 4; mi++) {
    long row0 = tile_m + rbase + mi*16;
    long voff = 0;
    int bb = 0;
    if (MODE == 5) {                   // batch lookup for v-transpose segment
      #pragma unroll
      for (int t = 1; t < B_; t++) bb += (row0 >= plan[2+t]) ? 1 : 0;
      voff = plan[2+bb];
    }
    #pragma unroll
    for (int ni = 0; ni < 4; ni++) {
      long col = tile_n + cbase + ni*16;
      float bv;
      if (MODE == 5) {
        const float* bp = (seg == 0) ? bias : (seg == 1) ? bias2 : bias3;
        bv = bp[col & 1023];
      } else if (MODE == 6) {
        bv = (blockIdx.z == 0) ? bias[col] : 0.f;
      } else {
        bv = bias[col];
      }
      #pragma unroll
      for (int r = 0; r < 4; r++) {
        long row = row0 + r;
        float v = acc[mi][ni][r] + bv;
        if (MODE == 2) v = v > 0.f ? v : 0.f;
        if (MODE == 0)      outf[row*Nn + col] = v;
        else if (MODE == 6) outf[row*Nn + col] = v;
        else if (MODE == 5) {
          __bf16* base = (__bf16*)Cv;
          long c = col & 1023;
          if (seg == 0)       base[row*D_ + c] = (__bf16)(v * scale);
          else if (seg == 1)  base[(long)M_*D_ + row*D_ + c] = (__bf16)v;
          else {
            long ll = row - voff;
            if (ll < LP_)
              base[2L*M_*D_ + (((long)bb*H_ + (c>>6))*HD_ + (c&63))*LP_ + ll] = (__bf16)v;
          }
        }
        else                ((__bf16*)Cv)[row*Nn + col] = (__bf16)v;
      }
    }
  }
}

// ---------------- flash attention (compacted rows) ----------------
__global__ __launch_bounds__(256, 2)
void attn_kernel(const __bf16* __restrict__ qb, const __bf16* __restrict__ kb,
                 const __bf16* __restrict__ vt, __bf16* __restrict__ ob,
                 const int* __restrict__ lens, const int* __restrict__ plan) {
  int col = blockIdx.x;               // b*H + h
  int b = col >> 4;
  int off = plan[2+b];
  int padLb = plan[3+b] - off;
  if ((int)blockIdx.y * 128 >= padLb) return;
  __shared__ __bf16 Ks[64*64];
  __shared__ __bf16 Vs[64*64];
  __shared__ __bf16 Ps[4][32*72];
  int tid = threadIdx.x, w = tid >> 6, l = tid & 63;
  int Lb = lens[2*b+1];
  int q0w = blockIdx.y*128 + w*32;
  const size_t bh  = (size_t)off*D_ + (size_t)(col & 15)*HD_;
  const size_t vtb = (size_t)col * HD_ * LP_;
  int nkt = (Lb + 63) >> 6;

  bf16x8 qf[2][2];
  #pragma unroll
  for (int mi = 0; mi < 2; mi++) {
    int qr = q0w + mi*16 + (l&15);
    if (qr > padLb-1) qr = padLb-1;
    const __bf16* qp = qb + bh + (size_t)qr*D_ + (l>>4)*8;
    qf[mi][0] = *(const bf16x8*)(qp);
    qf[mi][1] = *(const bf16x8*)(qp + 32);
  }
  bf16x8 ones;
  #pragma unroll
  for (int j = 0; j < 8; j++) ones[j] = (__bf16)1.0f;

  floatx4 oacc[2][4] = {};
  floatx4 lacc[2] = {};

  for (int kt = 0; kt < nkt; kt++) {
    int kbase = kt*64;
    {
      int krow = w*16 + (l>>3);
      int cb = (l&7) ^ (krow & 7);
      const __bf16* gk = kb + bh + (size_t)(kbase + krow)*D_ + cb*8;
      const __bf16* lk = Ks + (w*16)*64;
      gl2lds16(gk,                lk);
      gl2lds16(gk + 8*(size_t)D_, lk + 8*64);
    }
    {
      int vrow = w*8 + (l>>3);
      int sb = (l&7) ^ (l>>3);
      const __bf16* gv = vt + vtb + (size_t)vrow*LP_ + kbase + sb*8;
      const __bf16* lv = Vs + (w*8)*64;
      gl2lds16(gv,                  lv);
      gl2lds16(gv + 32*(size_t)LP_, lv + 32*64);
    }
    __syncthreads();

    floatx4 s4[2][4] = {};
    #pragma unroll
    for (int ks = 0; ks < 2; ks++) {
      #pragma unroll
      for (int ni = 0; ni < 4; ni++) {
        int n = ni*16 + (l&15);
        int blk = (ks*4 + (l>>4)) ^ (n & 7);
        bf16x8 kf = *(const bf16x8*)(Ks + n*64 + blk*8);
        s4[0][ni] = __builtin_amdgcn_mfma_f32_16x16x32_bf16(qf[0][ks], kf, s4[0][ni], 0, 0, 0);
        s4[1][ni] = __builtin_amdgcn_mfma_f32_16x16x32_bf16(qf[1][ks], kf, s4[1][ni], 0, 0, 0);
      }
    }
    #pragma unroll
    for (int mi = 0; mi < 2; mi++) {
      #pragma unroll
      for (int ni = 0; ni < 4; ni++) {
        int key = kbase + ni*16 + (l&15);
        bool valid = key < Lb;
        #pragma unroll
        for (int r = 0; r < 4; r++) {
          float sv = valid ? fminf(s4[mi][ni][r], 30.f) : -1e9f;
          float p = __expf(sv);
          Ps[w][(mi*16 + (l>>4)*4 + r)*72 + ni*16 + (l&15)] = (__bf16)p;
        }
      }
    }
    #pragma unroll
    for (int ks = 0; ks < 2; ks++) {
      bf16x8 pf0 = *(const bf16x8*)(&Ps[w][(l&15)*72 + ks*32 + (l>>4)*8]);
      bf16x8 pf1 = *(const bf16x8*)(&Ps[w][(16 + (l&15))*72 + ks*32 + (l>>4)*8]);
      lacc[0] = __builtin_amdgcn_mfma_f32_16x16x32_bf16(pf0, ones, lacc[0], 0, 0, 0);
      lacc[1] = __builtin_amdgcn_mfma_f32_16x16x32_bf16(pf1, ones, lacc[1], 0, 0, 0);
      #pragma unroll
      for (int ni = 0; ni < 4; ni++) {
        int n = ni*16 + (l&15);
        int blk = (ks*4 + (l>>4)) ^ (n & 7);
        bf16x8 vf = *(const bf16x8*)(Vs + n*64 + blk*8);
        oacc[0][ni] = __builtin_amdgcn_mfma_f32_16x16x32_bf16(pf0, vf, oacc[0][ni], 0, 0, 0);
        oacc[1][ni] = __builtin_amdgcn_mfma_f32_16x16x32_bf16(pf1, vf, oacc[1][ni], 0, 0, 0);
      }
    }
    __syncthreads();
  }

  #pragma unroll
  for (int mi = 0; mi < 2; mi++) {
    #pragma unroll
    for (int ni = 0; ni < 4; ni++) {
      #pragma unroll
      for (int r = 0; r < 4; r++) {
        int qrow = q0w + mi*16 + (l>>4)*4 + r;
        if (qrow < padLb) {
          float ov = oacc[mi][ni][r] / lacc[mi][r];
          ob[bh + (size_t)qrow*D_ + ni*16 + (l&15)] = (__bf16)ov;
        }
      }
    }
  }
}

// ---------------- post-norm LN: x = LN(x + t [+ t2])*s + b ----------------
__global__ void ln_kernel(__bf16* __restrict__ x, const float* __restrict__ t,
                          const float* __restrict__ t2,
                          const float* __restrict__ sc, const float* __restrict__ bi,
                          const int* __restrict__ plan) {
  int row = blockIdx.x;
  if (row >= plan[1]) return;
  __shared__ float red[2][4];
  int tid = threadIdx.x;
  const float* tr = t + (size_t)row * D_;
  const float* tr2 = t2 ? t2 + (size_t)row * D_ : nullptr;
  __bf16* xr = x + (size_t)row * D_;
  float v[4], s1 = 0.f, s2 = 0.f;
  #pragma unroll
  for (int j = 0; j < 4; j++) {
    int i = tid + j*256;
    float val = (float)xr[i] + tr[i];
    if (tr2) val += tr2[i];
    v[j] = val; s1 += val; s2 += val*val;
  }
  #pragma unroll
  for (int off = 1; off < 64; off <<= 1) {
    s1 += __shfl_xor(s1, off, 64);
    s2 += __shfl_xor(s2, off, 64);
  }
  int w = tid >> 6, l = tid & 63;
  if (l == 0) { red[0][w] = s1; red[1][w] = s2; }
  __syncthreads();
  s1 = red[0][0] + red[0][1] + red[0][2] + red[0][3];
  s2 = red[1][0] + red[1][1] + red[1][2] + red[1][3];
  float mean = s1 * (1.f/D_);
  float var  = s2 * (1.f/D_) - mean*mean;
  float rstd = rsqrtf(var + 1e-5f);
  #pragma unroll
  for (int j = 0; j < 4; j++) {
    int i = tid + j*256;
    xr[i] = (__bf16)((v[j] - mean)*rstd*sc[i] + bi[i]);
  }
}

// ---------------- final ----------------
__global__ void out_kernel(const __bf16* __restrict__ x, const float* __restrict__ wv,
                           const int* __restrict__ plan, float* __restrict__ out) {
  __shared__ float red[4];
  int b = blockIdx.x, tid = threadIdx.x;
  const __bf16* xr = x + (size_t)plan[2+b] * D_;
  float s = 0.f;
  #pragma unroll
  for (int j = 0; j < 4; j++) {
    int i = tid + j*256;
    s += (float)xr[i] * wv[i];
  }
  #pragma unroll
  for (int off = 1; off < 64; off <<= 1) s += __shfl_xor(s, off, 64);
  int w = tid >> 6, l = tid & 63;
  if (l == 0) red[w] = s;
  __syncthreads();
  if (tid == 0) out[b] = red[0] + red[1] + red[2] + red[3];
}

// ---------------- launch ----------------
extern "C" void kernel_launch(void* const* d_in, const int* in_sizes, int n_in,
                              void* d_out, int out_size, void* d_ws, size_t ws_size,
                              hipStream_t stream) {
  (void)in_sizes; (void)n_in; (void)out_size;
  const float* text   = (const float*)d_in[0];
  const float* speech = (const float*)d_in[1];
  const int*   tmask  = (const int*)d_in[2];
  const int*   smask  = (const int*)d_in[3];
  const float* cls    = (const float*)d_in[4];
  const float* sep    = (const float*)d_in[5];
  const float* Wq     = (const float*)d_in[6];
  const float* bq     = (const float*)d_in[7];
  const float* Wk     = (const float*)d_in[8];
  const float* bk     = (const float*)d_in[9];
  const float* Wv     = (const float*)d_in[10];
  const float* bv     = (const float*)d_in[11];
  const float* Wo     = (const float*)d_in[12];
  const float* bo     = (const float*)d_in[13];
  const float* ln1s   = (const float*)d_in[14];
  const float* ln1b   = (const float*)d_in[15];
  const float* fc1w   = (const float*)d_in[16];
  const float* fc1b   = (const float*)d_in[17];
  const float* fc2w   = (const float*)d_in[18];
  const float* fc2b   = (const float*)d_in[19];
  const float* ln2s   = (const float*)d_in[20];
  const float* ln2b   = (const float*)d_in[21];
  const float* outw   = (const float*)d_in[22];

  const size_t MD = (size_t)M_ * D_;
  char* ws = (char*)d_ws;
  int*    lens = (int*)ws;
  int*    plan = (int*)(ws + 128);
  __bf16* xbf  = (__bf16*)(ws + 256);
  __bf16* act  = (__bf16*)(ws + 256 + MD*2);
  float*  tmp  = (float*) (ws + 256 + MD*2 + 4*MD*2);
  __bf16* wt   = (__bf16*)(ws + 256 + MD*2 + 4*MD*2 + MD*4);

  __bf16* qb   = act;
  __bf16* kb   = act + MD;
  __bf16* vtG  = act + 2*MD;                             // [B,H,HD,LP]
  __bf16* obuf = act + 3*MD;
  __bf16* hb   = act;                                    // [M, F] in FFN phase

  const size_t DD = (size_t)D_*D_;
  const size_t DF = (size_t)D_*F_;
  __bf16* wqkvT = wt;                                    // [NL][3*1024][1024]
  __bf16* woT   = wt + 12*DD;
  __bf16* fc1T  = wt + 16*DD;
  __bf16* fc2T  = wt + 16*DD + 4*DF;
  // optional second split-K accumulator after the weight arena
  size_t wt_bytes = (16*DD + 8*DF) * sizeof(__bf16);
  float* tmp2 = (float*)((char*)wt + wt_bytes);
  size_t need2 = (256 + MD*2 + 4*MD*2 + MD*4) + wt_bytes + MD*4;
  const bool splitk = ws_size >= need2;                  // deterministic per run: graph-safe

  lens_kernel<<<B_, 256, 0, stream>>>(tmask, smask, lens);
  plan_kernel<<<1, 64, 0, stream>>>(lens, plan);

  transpose_kernel<<<dim3(D_/32, D_/32, NL_), 256, 0, stream>>>(Wq, wqkvT,        D_, D_, 3*DD);
  transpose_kernel<<<dim3(D_/32, D_/32, NL_), 256, 0, stream>>>(Wk, wqkvT + DD,   D_, D_, 3*DD);
  transpose_kernel<<<dim3(D_/32, D_/32, NL_), 256, 0, stream>>>(Wv, wqkvT + 2*DD, D_, D_, 3*DD);
  transpose_kernel<<<dim3(D_/32, D_/32, NL_), 256, 0, stream>>>(Wo, woT,  D_, D_, DD);
  transpose_kernel<<<dim3(F_/32, D_/32, NL_), 256, 0, stream>>>(fc1w, fc1T, D_, F_, DF);
  transpose_kernel<<<dim3(D_/32, F_/32, NL_), 256, 0, stream>>>(fc2w, fc2T, F_, D_, DF);

  build_x_kernel<<<dim3(LP_, B_), 256, 0, stream>>>(text, speech, cls, sep, lens, plan, xbf);

  for (int lyr = 0; lyr < NL_; lyr++) {
    // fused QKV: N=3072 packed weights; epilogue routes q(*0.125)/k/v(transposed)
    gemm_kernel<5><<<dim3(24, M_/128), 256, 0, stream>>>(
        xbf, wqkvT + (size_t)lyr*3*DD, bq + lyr*D_, bk + lyr*D_, bv + lyr*D_,
        act, plan, 3072, D_, D_, 0.125f);
    attn_kernel<<<dim3(B_*H_, (LP_+127)/128), 256, 0, stream>>>(qb, kb, vtG, obuf, lens, plan);
    gemm_kernel<0><<<dim3(D_/128, M_/128), 256, 0, stream>>>(
        obuf, woT + (size_t)lyr*DD, bo + lyr*D_, nullptr, nullptr, tmp, plan, D_, D_, D_, 1.f);
    ln_kernel<<<M_, 256, 0, stream>>>(xbf, tmp, nullptr, ln1s + lyr*D_, ln1b + lyr*D_, plan);
    gemm_kernel<2><<<dim3(F_/128, M_/128), 256, 0, stream>>>(
        xbf, fc1T + (size_t)lyr*DF, fc1b + lyr*F_, nullptr, nullptr, hb, plan, F_, D_, D_, 1.f);
    if (splitk) {
      // fc2 split-K=2, atomic-free: z writes its partial to tmp (z=0, +bias) / tmp2 (z=1)
      gemm_kernel<6><<<dim3(D_/128, M_/128, 2), 256, 0, stream>>>(
          hb, fc2T + (size_t)lyr*DF, fc2b + lyr*D_, nullptr, nullptr, tmp, plan, D_, F_, 2048, 1.f);
      ln_kernel<<<M_, 256, 0, stream>>>(xbf, tmp, tmp2, ln2s + lyr*D_, ln2b + lyr*D_, plan);
    } else {
      gemm_kernel<6><<<dim3(D_/128, M_/128, 1), 256, 0, stream>>>(
          hb, fc2T + (size_t)lyr*DF, fc2b + lyr*D_, nullptr, nullptr, tmp, plan, D_, F_, F_, 1.f);
      ln_kernel<<<M_, 256, 0, stream>>>(xbf, tmp, nullptr, ln2s + lyr*D_, ln2b + lyr*D_, plan);
    }
  }

  out_kernel<<<B_, 256, 0, stream>>>(xbf, outw, plan, (float*)d_out);
}